// Round 11
// baseline (501.181 us; speedup 1.0000x reference)
//
#include <hip/hip_runtime.h>
#include <hip/hip_bf16.h>
#include <math.h>

// ---------------------------------------------------------------------------
// PromptDurationMemoryEncoder — MI355X (gfx950)
// Conv GEMMs: FP8 e4m3 data (x64 scale), MX-scaled K=128 MFMA (unit scales),
// 128x64 tile -> 3 blocks/CU residency.
// ---------------------------------------------------------------------------

typedef unsigned short u16;
typedef unsigned char u8;
typedef __attribute__((ext_vector_type(8))) short short8;
typedef __attribute__((ext_vector_type(4))) float f32x4;
typedef __attribute__((ext_vector_type(8))) int int8x;

constexpr int B_ = 32, T_ = 2048, D_ = 512, V_ = 4096, M_ = 64, TP_ = 2050;

// output offsets (floats)
constexpr int OUT_GR = 0;          // [32]
constexpr int OUT_SUM = 32;        // [32*512]
constexpr int OUT_RV = 16416;      // [32*64]
constexpr int OUT_VAR = 18464;     // [32*64]
constexpr int OUT_COV = 20512;     // [32*64]
constexpr int OUT_FIT = 22560;     // [32*2048]

// workspace byte offsets
constexpr size_t OFF_S0 = 0;
constexpr size_t OFF_S1 = OFF_S0 + 2048 * 4;
constexpr size_t OFF_S2 = OFF_S1 + 2048 * 4;
constexpr size_t OFF_SH = OFF_S2 + 2048 * 4;          // 16384 f32
constexpr size_t OFF_SH2 = OFF_SH + 16384 * 4;
constexpr size_t ZERO_BYTES = OFF_SH2 + 16384 * 4;    // 155648
constexpr size_t OFF_RESID = ZERO_BYTES;              // 65536 f32
constexpr size_t OFF_GR = OFF_RESID + 65536 * 4;
constexpr size_t OFF_SUP = OFF_GR + 128;
constexpr size_t OFF_SPC = OFF_SUP + 128;
constexpr size_t OFF_RVW = OFF_SPC + 128;             // 2048 f32
constexpr size_t OFF_WTIN = OFF_RVW + 8192;           // 512*512 bf16
constexpr size_t OFF_WTC1 = OFF_WTIN + 524288;        // 3*512*512 fp8
constexpr size_t OFF_WTC2 = OFF_WTC1 + 786432;        // 3*512*512 fp8
constexpr size_t OFF_CKB = OFF_WTC2 + 786432;         // 64*512 bf16
constexpr size_t OFF_EMBB = OFF_CKB + 65536;          // 4096*512 bf16
constexpr size_t OFF_TBL = OFF_EMBB + 4194304;        // 4096*512 bf16 (slot sized f32)
constexpr size_t OFF_H0 = OFF_TBL + 8388608;          // B*TP*D fp8 (x64 scale)
constexpr size_t OFF_H1 = OFF_H0 + 33587200;          // B*TP*D fp8 (x64 scale)
constexpr size_t OFF_H2 = OFF_H1 + 33587200;          // B*T*D bf16 (final h)
constexpr size_t OFF_ATTN = OFF_H2 + 67108864;        // 65536*64 f32

__device__ __forceinline__ float clamp01(float x) { return fminf(fmaxf(x, 0.f), 1.f); }
__device__ __forceinline__ float b2f(u16 u) { return __uint_as_float(((unsigned)u) << 16); }
__device__ __forceinline__ u16 f2b(float f) {
  unsigned u = __float_as_uint(f);
  unsigned r = (u + 0x7FFFu + ((u >> 16) & 1u)) >> 16;
  return (u16)r;
}
__device__ __forceinline__ u8 f2fp8(float f) {
  return (u8)(__builtin_amdgcn_cvt_pk_fp8_f32(f, f, 0, false) & 0xFF);
}
__device__ __forceinline__ float gelu_f(float x) {
  return 0.5f * x * (1.0f + erff(x * 0.7071067811865475f));
}
__device__ __forceinline__ void gload16(const void* g, void* l) {
  __builtin_amdgcn_global_load_lds((const __attribute__((address_space(1))) void*)g,
                                   (__attribute__((address_space(3))) void*)l, 16, 0, 0);
}

// ---------------------------------------------------------------------------
// 1. median + residual + support counts (register keys, wave-shfl reduce)
// ---------------------------------------------------------------------------
__global__ __launch_bounds__(256) void median_kernel(
    const float* __restrict__ dur, const float* __restrict__ vmask,
    const float* __restrict__ smask, float* __restrict__ out0,
    float* __restrict__ gr, float* __restrict__ sup, float* __restrict__ spc,
    float* __restrict__ resid) {
  int b = blockIdx.x, tid = threadIdx.x;
  int wv = tid >> 6, lane = tid & 63;
  __shared__ float wredf[8];
  __shared__ int wredi[4];
  unsigned keys[8];
  float ldv[8], vmv[8];
  float vs = 0.f, ss = 0.f;
#pragma unroll
  for (int j = 0; j < 8; ++j) {
    int t = j * 256 + tid;
    float vm = clamp01(vmask[b * T_ + t]);
    float sm = clamp01(smask[b * T_ + t]) * vm;
    vs += vm; ss += sm;
    float ld = logf(fmaxf(dur[b * T_ + t], 1e-4f)) * vm;
    ldv[j] = ld; vmv[j] = vm;
    unsigned bits = __float_as_uint(ld);
    unsigned key = (bits & 0x80000000u) ? ~bits : (bits | 0x80000000u);
    keys[j] = (sm > 0.5f) ? key : 0xFFFFFFFFu;
  }
  for (int o = 32; o > 0; o >>= 1) { vs += __shfl_xor(vs, o); ss += __shfl_xor(ss, o); }
  if (lane == 0) { wredf[wv] = vs; wredf[4 + wv] = ss; }
  __syncthreads();
  float s_sup = wredf[0] + wredf[1] + wredf[2] + wredf[3];
  float s_spc = wredf[4] + wredf[5] + wredf[6] + wredf[7];
  int n = (int)(s_spc + 0.5f);
  int target = (n > 0) ? ((n - 1) / 2 + 1) : 1;
  unsigned lo = 0u, hi = 0xFFFFFFFFu;
  for (int it = 0; it < 32; ++it) {
    unsigned mid = lo + ((hi - lo) >> 1);
    int c = 0;
#pragma unroll
    for (int j = 0; j < 8; ++j) c += (keys[j] <= mid) ? 1 : 0;
    for (int o = 32; o > 0; o >>= 1) c += __shfl_xor(c, o);
    __syncthreads();
    if (lane == 0) wredi[wv] = c;
    __syncthreads();
    int tot = wredi[0] + wredi[1] + wredi[2] + wredi[3];
    if (tot >= target) hi = mid; else lo = mid + 1;
  }
  float med = 0.f;
  if (n > 0) {
    unsigned K = lo;
    unsigned ub = (K & 0x80000000u) ? (K & 0x7FFFFFFFu) : ~K;
    med = __uint_as_float(ub);
  }
  if (tid == 0) { out0[OUT_GR + b] = med; gr[b] = med; sup[b] = s_sup; spc[b] = s_spc; }
#pragma unroll
  for (int j = 0; j < 8; ++j) {
    int t = j * 256 + tid;
    resid[b * T_ + t] = (ldv[j] - med) * vmv[j];
  }
}

// ---------------------------------------------------------------------------
// 2a. weight transpose: W_in -> bf16; W_c1/W_c2 -> fp8 e4m3 (x64 scale)
// ---------------------------------------------------------------------------
__global__ __launch_bounds__(256) void wpack_kernel(
    const float* __restrict__ W_in, const float* __restrict__ W_c1,
    const float* __restrict__ W_c2, u16* __restrict__ wtin,
    u8* __restrict__ wtc1, u8* __restrict__ wtc2) {
  __shared__ float tile[64][65];
  int x = blockIdx.x;        // 0..447
  int m = x >> 6, tl = x & 63;
  int kt = tl >> 3, nt = tl & 7;
  const float* src;
  if (m == 0) src = W_in;
  else if (m <= 3) src = W_c1 + (size_t)(m - 1) * 262144;
  else src = W_c2 + (size_t)(m - 4) * 262144;
  int tid = threadIdx.x;
#pragma unroll
  for (int j = 0; j < 16; ++j) {
    int idx = j * 256 + tid;
    int r = idx >> 6, c = idx & 63;
    tile[r][c] = src[(size_t)(kt * 64 + r) * 512 + nt * 64 + c];
  }
  __syncthreads();
  if (m == 0) {
#pragma unroll
    for (int j = 0; j < 16; ++j) {
      int idx = j * 256 + tid;
      int r = idx >> 6, c = idx & 63;
      wtin[(size_t)(nt * 64 + r) * 512 + kt * 64 + c] = f2b(tile[c][r]);
    }
  } else {
    u8* dst = (m <= 3) ? wtc1 + (size_t)(m - 1) * 262144
                       : wtc2 + (size_t)(m - 4) * 262144;
#pragma unroll
    for (int j = 0; j < 16; ++j) {
      int idx = j * 256 + tid;
      int r = idx >> 6, c = idx & 63;
      dst[(size_t)(nt * 64 + r) * 512 + kt * 64 + c] = f2fp8(tile[c][r] * 64.f);
    }
  }
}

// ---------------------------------------------------------------------------
// 2b. straight f32 -> bf16 convert for ck (32768) and emb (2097152)
// ---------------------------------------------------------------------------
__global__ __launch_bounds__(256) void convert_kernel(
    const float* __restrict__ ck, const float* __restrict__ emb,
    u16* __restrict__ ckb, u16* __restrict__ embb) {
  int idx = blockIdx.x * 256 + threadIdx.x;   // one per 4 elements; 532480 total
  float4 v;
  u16* dst;
  if (idx < 8192) {
    v = reinterpret_cast<const float4*>(ck)[idx];
    dst = ckb + idx * 4;
  } else {
    int i = idx - 8192;
    v = reinterpret_cast<const float4*>(emb)[i];
    dst = embb + (size_t)i * 4;
  }
  uint2 o;
  o.x = (unsigned)f2b(v.x) | ((unsigned)f2b(v.y) << 16);
  o.y = (unsigned)f2b(v.z) | ((unsigned)f2b(v.w) << 16);
  *reinterpret_cast<uint2*>(dst) = o;
}

// ---------------------------------------------------------------------------
// 3a. plain MFMA GEMM (tbl = emb @ W_in): 64x128 tile -> 256 blocks, bf16 out
// ---------------------------------------------------------------------------
__global__ __launch_bounds__(256) void gemm_plain_kernel(
    const u16* __restrict__ A, const u16* __restrict__ Bt,
    const float* __restrict__ bias, u16* __restrict__ Cout) {
  __shared__ u16 ldsA[64 * 64];
  __shared__ u16 ldsB[128 * 64];
  const int tid = threadIdx.x;
  const int row0 = blockIdx.x * 64;
  const int col0 = blockIdx.y * 128;

  f32x4 acc[2][4] = {};
  const int wv = tid >> 6, lane = tid & 63;
  const int wr = (wv >> 1) << 5;           // 0,32
  const int wc = (wv & 1) << 6;            // 0,64
  const int lr = lane & 15, cgrp = lane >> 4;

  const u16* Ab = A + (size_t)row0 * 512;
  const u16* Bb = Bt + (size_t)col0 * 512;
  for (int k0 = 0; k0 < 512; k0 += 64) {
    if (k0) __syncthreads();
#pragma unroll
    for (int j = 0; j < 2; ++j) {
      int ci = j * 256 + tid;
      int r = ci >> 3, s = ci & 7;
      int gs = s ^ (r & 7);
      gload16(Ab + (size_t)r * 512 + k0 + gs * 8, &ldsA[ci * 8]);
    }
#pragma unroll
    for (int j = 0; j < 4; ++j) {
      int ci = j * 256 + tid;
      int r = ci >> 3, s = ci & 7;
      int gs = s ^ (r & 7);
      gload16(Bb + (size_t)r * 512 + k0 + gs * 8, &ldsB[ci * 8]);
    }
    __syncthreads();
#pragma unroll
    for (int kk = 0; kk < 2; ++kk) {
      short8 af[2], bfr[4];
#pragma unroll
      for (int m = 0; m < 2; ++m) {
        int r = wr + m * 16 + lr;
        int s = (kk * 4 + cgrp) ^ (r & 7);
        af[m] = *reinterpret_cast<const short8*>(&ldsA[(r << 6) + (s << 3)]);
      }
#pragma unroll
      for (int n = 0; n < 4; ++n) {
        int r = wc + n * 16 + lr;
        int s = (kk * 4 + cgrp) ^ (r & 7);
        bfr[n] = *reinterpret_cast<const short8*>(&ldsB[(r << 6) + (s << 3)]);
      }
#pragma unroll
      for (int m = 0; m < 2; ++m)
#pragma unroll
        for (int n = 0; n < 4; ++n)
          acc[m][n] = __builtin_amdgcn_mfma_f32_16x16x32_bf16(af[m], bfr[n], acc[m][n], 0, 0, 0);
    }
  }
#pragma unroll
  for (int m = 0; m < 2; ++m)
#pragma unroll
    for (int n = 0; n < 4; ++n)
#pragma unroll
      for (int r = 0; r < 4; ++r) {
        int lrow = wr + m * 16 + (lane >> 4) * 4 + r;
        int lcol = wc + n * 16 + (lane & 15);
        Cout[(size_t)(row0 + lrow) * 512 + col0 + lcol] =
            f2b(acc[m][n][r] + bias[col0 + lcol]);
      }
}

// ---------------------------------------------------------------------------
// 3b. tap-fused conv GEMM in FP8 — 128x64 tile, 3 blocks/CU, r10 staging,
//     MX-scaled K=128 MFMA (mfma_scale_f32_16x16x128_f8f6f4, unit E8M0
//     scales = 0x7F). Lane (lr,cgrp) fragment = logical chunks 2cgrp,2cgrp+1
//     of its row (inverse-XOR slot reads); A and B share the identical
//     (lane,byte)->k map so the internal permutation cancels.
// ---------------------------------------------------------------------------
template <int PADOUT, int OUTFP8>
__global__ __launch_bounds__(256) void conv_gemm_kernel(
    const u8* __restrict__ A, const u8* __restrict__ Bt,
    const float* __restrict__ bias, void* __restrict__ Cout) {
  __shared__ u8 ldsA[130 * 128];             // 16.6 KB
  __shared__ u8 ldsB[3 * 64 * 128];          // 24 KB
  const int tid = threadIdx.x;
  const int id = blockIdx.x;                 // 0..4095
  const int wg = (id & 7) * 512 + (id >> 3); // XCD swizzle
  const int rb = wg >> 3, cb = wg & 7;
  const int row0 = rb * 128, col0 = cb * 64;
  const int b = row0 >> 11, t0 = row0 & 2047;
  const size_t aBase = ((size_t)b * TP_ + t0) * 512;
  const size_t oBase = PADOUT ? ((size_t)b * TP_ + 1 + t0) : (size_t)row0;

  f32x4 acc[4][2] = {};
  const int wv = tid >> 6, lane = tid & 63;
  const int wr = (wv >> 1) << 6;             // 0,64
  const int wc = (wv & 1) << 5;              // 0,32
  const int lr = lane & 15, cgrp = lane >> 4;

  const u8* Ab = A + aBase;
  for (int k0 = 0; k0 < 512; k0 += 128) {
    if (k0) __syncthreads();
    // stage A window: 130 rows x 8 16B-chunks = 1040
#pragma unroll
    for (int j = 0; j < 5; ++j) {
      int ci = j * 256 + tid;
      if (ci < 1040) {
        int r = ci >> 3, s = ci & 7;
        int gs = s ^ (r & 7);
        gload16(Ab + (size_t)r * 512 + k0 + gs * 16, &ldsA[ci * 16]);
      }
    }
    // stage B: 3 taps x 64 cols x 8 chunks = 1536
#pragma unroll
    for (int j = 0; j < 6; ++j) {
      int ci = j * 256 + tid;
      int r = ci >> 3, s = ci & 7;           // r = tap*64 + n (0..191)
      int tap = r >> 6, n = r & 63;
      int gs = s ^ (r & 7);
      gload16(Bt + ((size_t)(tap * 512 + col0 + n)) * 512 + k0 + gs * 16, &ldsB[ci * 16]);
    }
    __syncthreads();
#pragma unroll
    for (int tap = 0; tap < 3; ++tap) {
      int8x af[4], bfr[2];
#pragma unroll
      for (int m = 0; m < 4; ++m) {
        int r = wr + m * 16 + lr + tap;      // window row 0..129
        int s0 = (2 * cgrp) ^ (r & 7);
        int s1 = (2 * cgrp + 1) ^ (r & 7);
        uint4 lo = *reinterpret_cast<const uint4*>(&ldsA[(r << 7) + (s0 << 4)]);
        uint4 hi = *reinterpret_cast<const uint4*>(&ldsA[(r << 7) + (s1 << 4)]);
        af[m][0] = (int)lo.x; af[m][1] = (int)lo.y; af[m][2] = (int)lo.z; af[m][3] = (int)lo.w;
        af[m][4] = (int)hi.x; af[m][5] = (int)hi.y; af[m][6] = (int)hi.z; af[m][7] = (int)hi.w;
      }
#pragma unroll
      for (int n = 0; n < 2; ++n) {
        int rB = tap * 64 + wc + n * 16 + lr;
        int s0 = (2 * cgrp) ^ (rB & 7);
        int s1 = (2 * cgrp + 1) ^ (rB & 7);
        uint4 lo = *reinterpret_cast<const uint4*>(&ldsB[(rB << 7) + (s0 << 4)]);
        uint4 hi = *reinterpret_cast<const uint4*>(&ldsB[(rB << 7) + (s1 << 4)]);
        bfr[n][0] = (int)lo.x; bfr[n][1] = (int)lo.y; bfr[n][2] = (int)lo.z; bfr[n][3] = (int)lo.w;
        bfr[n][4] = (int)hi.x; bfr[n][5] = (int)hi.y; bfr[n][6] = (int)hi.z; bfr[n][7] = (int)hi.w;
      }
#pragma unroll
      for (int m = 0; m < 4; ++m)
#pragma unroll
        for (int n = 0; n < 2; ++n)
          acc[m][n] = __builtin_amdgcn_mfma_scale_f32_16x16x128_f8f6f4(
              af[m], bfr[n], acc[m][n], 0, 0, 0, 0x7F7F7F7F, 0, 0x7F7F7F7F);
    }
  }
  // epilogue: C/D layout col=lane&15, row=(lane>>4)*4+reg
#pragma unroll
  for (int m = 0; m < 4; ++m)
#pragma unroll
    for (int n = 0; n < 2; ++n)
#pragma unroll
      for (int r = 0; r < 4; ++r) {
        int lrow = wr + m * 16 + (lane >> 4) * 4 + r;
        int lcol = wc + n * 16 + (lane & 15);
        float v = acc[m][n][r] * (1.f / 4096.f) + bias[col0 + lcol];
        v = gelu_f(v);
        if (OUTFP8)
          ((u8*)Cout)[(oBase + lrow) * 512 + col0 + lcol] = f2fp8(v * 64.f);
        else
          ((u16*)Cout)[(oBase + lrow) * 512 + col0 + lcol] = f2b(v);
      }
}

// ---------------------------------------------------------------------------
// 4. gather: h0[b,t] = fp8( (tbl[unit] + resid*W_in[512] + sil*W_in[513]) * 64 )
// ---------------------------------------------------------------------------
__global__ __launch_bounds__(256) void gather_kernel(
    const int* __restrict__ units, const float* __restrict__ resid,
    const float* __restrict__ vmask, const float* __restrict__ smask,
    const u16* __restrict__ tbl, const float* __restrict__ w512,
    const float* __restrict__ w513, u8* __restrict__ h0p, u8* __restrict__ h1p) {
  int row = blockIdx.x * 4 + (threadIdx.x >> 6);  // 0..B*TP-1
  int b = row / TP_, tp = row - b * TP_;
  int lane = threadIdx.x & 63;
  size_t o = (size_t)row * 512 + lane * 8;
  if (tp == 0 || tp == TP_ - 1) {
    uint2 z = {0, 0};
    *reinterpret_cast<uint2*>(&h0p[o]) = z;
    *reinterpret_cast<uint2*>(&h1p[o]) = z;
    return;
  }
  int t = tp - 1, g = b * T_ + t;
  float vm = clamp01(vmask[g]);
  float sm = clamp01(smask[g]) * vm;
  float sil = fmaxf(vm - sm, 0.f);
  float rs = resid[g];
  int u = units[g];
  uint4 tv = *reinterpret_cast<const uint4*>(tbl + (size_t)u * 512 + lane * 8);
  float tr[8];
  tr[0] = __uint_as_float(tv.x << 16); tr[1] = __uint_as_float(tv.x & 0xFFFF0000u);
  tr[2] = __uint_as_float(tv.y << 16); tr[3] = __uint_as_float(tv.y & 0xFFFF0000u);
  tr[4] = __uint_as_float(tv.z << 16); tr[5] = __uint_as_float(tv.z & 0xFFFF0000u);
  tr[6] = __uint_as_float(tv.w << 16); tr[7] = __uint_as_float(tv.w & 0xFFFF0000u);
  const float* a = w512 + lane * 8;
  const float* c = w513 + lane * 8;
  float f[8];
#pragma unroll
  for (int j = 0; j < 8; ++j) f[j] = (tr[j] + rs * a[j] + sil * c[j]) * 64.f;
  unsigned lo = __builtin_amdgcn_cvt_pk_fp8_f32(f[0], f[1], 0, false);
  lo = __builtin_amdgcn_cvt_pk_fp8_f32(f[2], f[3], lo, true);
  unsigned hi = __builtin_amdgcn_cvt_pk_fp8_f32(f[4], f[5], 0, false);
  hi = __builtin_amdgcn_cvt_pk_fp8_f32(f[6], f[7], hi, true);
  uint2 val = {lo, hi};
  *reinterpret_cast<uint2*>(&h0p[o]) = val;
}

// ---------------------------------------------------------------------------
// 5. fused LayerNorm (in-place, * valid) + speech-masked pooling sums
// ---------------------------------------------------------------------------
__global__ __launch_bounds__(256) void lnpool_kernel(
    u16* __restrict__ h, const float* __restrict__ lnw,
    const float* __restrict__ lnb, const float* __restrict__ vmask,
    const float* __restrict__ smask, float* __restrict__ Sh,
    float* __restrict__ Sh2) {
  int b = blockIdx.y, chunk = blockIdx.x, tid = threadIdx.x;
  int lane = tid & 63, tof = tid >> 6;
  __shared__ float shA[512], shQ[512];
  shA[tid] = 0.f; shA[tid + 256] = 0.f;
  shQ[tid] = 0.f; shQ[tid + 256] = 0.f;
  __syncthreads();
  int d8 = lane * 8;
  float wv_[8], bv_[8];
#pragma unroll
  for (int j = 0; j < 8; ++j) { wv_[j] = lnw[d8 + j]; bv_[j] = lnb[d8 + j]; }
  float a[8] = {}, q[8] = {};
  for (int i = 0; i < 32; ++i) {
    int t = chunk * 128 + i * 4 + tof;
    int g = b * T_ + t;
    float vm = clamp01(vmask[g]);
    float sp = clamp01(smask[g]) * vm;
    u16* p = h + (size_t)g * 512 + d8;
    uint4 raw = *reinterpret_cast<const uint4*>(p);
    float x[8];
    x[0] = __uint_as_float(raw.x << 16); x[1] = __uint_as_float(raw.x & 0xFFFF0000u);
    x[2] = __uint_as_float(raw.y << 16); x[3] = __uint_as_float(raw.y & 0xFFFF0000u);
    x[4] = __uint_as_float(raw.z << 16); x[5] = __uint_as_float(raw.z & 0xFFFF0000u);
    x[6] = __uint_as_float(raw.w << 16); x[7] = __uint_as_float(raw.w & 0xFFFF0000u);
    float s = 0.f, sq = 0.f;
#pragma unroll
    for (int j = 0; j < 8; ++j) { s += x[j]; sq = fmaf(x[j], x[j], sq); }
    for (int o = 32; o > 0; o >>= 1) { s += __shfl_xor(s, o); sq += __shfl_xor(sq, o); }
    float mu = s * (1.f / 512.f);
    float var = fmaxf(sq * (1.f / 512.f) - mu * mu, 0.f);
    float rstd = rsqrtf(var + 1e-5f);
    u16 ob[8];
#pragma unroll
    for (int j = 0; j < 8; ++j) {
      float y = (x[j] - mu) * rstd * wv_[j] + bv_[j];
      ob[j] = f2b(y * vm);
      float yr = b2f(ob[j]);
      a[j] = fmaf(yr, sp, a[j]);
      q[j] = fmaf(yr * yr, sp, q[j]);
    }
    uint4 val;
    val.x = (unsigned)ob[0] | ((unsigned)ob[1] << 16);
    val.y = (unsigned)ob[2] | ((unsigned)ob[3] << 16);
    val.z = (unsigned)ob[4] | ((unsigned)ob[5] << 16);
    val.w = (unsigned)ob[6] | ((unsigned)ob[7] << 16);
    *reinterpret_cast<uint4*>(p) = val;
  }
#pragma unroll
  for (int j = 0; j < 8; ++j) {
    atomicAdd(&shA[d8 + j], a[j]);
    atomicAdd(&shQ[d8 + j], q[j]);
  }
  __syncthreads();
  atomicAdd(&Sh[b * 512 + tid], shA[tid]);
  atomicAdd(&Sh[b * 512 + tid + 256], shA[tid + 256]);
  atomicAdd(&Sh2[b * 512 + tid], shQ[tid]);
  atomicAdd(&Sh2[b * 512 + tid + 256], shQ[tid + 256]);
}

// ---------------------------------------------------------------------------
// 6. score: MFMA h@ck^T + softmax + attn store + role moments
// ---------------------------------------------------------------------------
__global__ __launch_bounds__(256) void score_kernel(
    const u16* __restrict__ h, const u16* __restrict__ ckb,
    const float* __restrict__ resid, const float* __restrict__ vmask,
    float* __restrict__ attn, float* __restrict__ S0, float* __restrict__ S1,
    float* __restrict__ S2) {
  __shared__ char smem[98304];           // ckl 64KB | ldsH 32KB ; reused as attn_lds
  __shared__ float s0s[64], s1s[64], s2s[64];
  u16* ckl = (u16*)smem;                 // [64 roles][512 k] swizzled
  u16* ldsH = (u16*)(smem + 65536);      // [256 rows][64 k] swizzled
  float* attn_lds = (float*)smem;        // [256][65] after compute

  const int tid = threadIdx.x;
  const int base = blockIdx.x * 256;     // global token base
  const int bq = base >> 11;             // batch index

#pragma unroll
  for (int it = 0; it < 16; ++it) {
    int ci = it * 256 + tid;             // 0..4095 (16B chunks)
    int m = ci >> 6, s = ci & 63;
    int sw = (s & 56) | ((s & 7) ^ (m & 7));
    *reinterpret_cast<uint4*>(&ckl[(m << 9) + (sw << 3)]) =
        *reinterpret_cast<const uint4*>(&ckb[(m << 9) + (s << 3)]);
  }
  if (tid < 64) { s0s[tid] = 0.f; s1s[tid] = 0.f; s2s[tid] = 0.f; }

  const int wv = tid >> 6, lane = tid & 63;
  const int lr = lane & 15, cgrp = lane >> 4;
  const int hi = lane >> 4, lf = lane & 15;
  f32x4 acc[4][4] = {};

  const u16* hb = h + (size_t)base * 512;
  for (int k0 = 0; k0 < 512; k0 += 64) {
    __syncthreads();
#pragma unroll
    for (int j = 0; j < 8; ++j) {
      int ci = j * 256 + tid;
      int r = ci >> 3, s = ci & 7;
      int gs = s ^ (r & 7);
      gload16(hb + (size_t)r * 512 + k0 + gs * 8, &ldsH[ci * 8]);
    }
    __syncthreads();
#pragma unroll
    for (int kk = 0; kk < 2; ++kk) {
      short8 af[4], bfr[4];
#pragma unroll
      for (int m = 0; m < 4; ++m) {
        int r = wv * 64 + m * 16 + lr;
        int s = (kk * 4 + cgrp) ^ (r & 7);
        af[m] = *reinterpret_cast<const short8*>(&ldsH[(r << 6) + (s << 3)]);
      }
#pragma unroll
      for (int n = 0; n < 4; ++n) {
        int r = n * 16 + lr;
        int s = (kk * 4 + cgrp) ^ (r & 7);
        bfr[n] = *reinterpret_cast<const short8*>(&ckl[(r << 9) + k0 + (s << 3)]);
      }
#pragma unroll
      for (int m = 0; m < 4; ++m)
#pragma unroll
        for (int n = 0; n < 4; ++n)
          acc[m][n] = __builtin_amdgcn_mfma_f32_16x16x32_bf16(af[m], bfr[n], acc[m][n], 0, 0, 0);
    }
  }
  __syncthreads();

  const float scale = 0.04419417382415922f;  // 1/sqrt(512)
  float s0p[4] = {0.f, 0.f, 0.f, 0.f};
  float s1p[4] = {0.f, 0.f, 0.f, 0.f};
  float s2p[4] = {0.f, 0.f, 0.f, 0.f};
#pragma unroll
  for (int m = 0; m < 4; ++m) {
#pragma unroll
    for (int rr = 0; rr < 4; ++rr) {
      int tl = wv * 64 + m * 16 + hi * 4 + rr;
      int tg = base + tl;
      float v[4];
#pragma unroll
      for (int n = 0; n < 4; ++n) v[n] = acc[m][n][rr] * scale;
      float mx = fmaxf(fmaxf(v[0], v[1]), fmaxf(v[2], v[3]));
      mx = fmaxf(mx, __shfl_xor(mx, 1));
      mx = fmaxf(mx, __shfl_xor(mx, 2));
      mx = fmaxf(mx, __shfl_xor(mx, 4));
      mx = fmaxf(mx, __shfl_xor(mx, 8));
      float e[4], sum = 0.f;
#pragma unroll
      for (int n = 0; n < 4; ++n) { e[n] = expf(v[n] - mx); sum += e[n]; }
      sum += __shfl_xor(sum, 1);
      sum += __shfl_xor(sum, 2);
      sum += __shfl_xor(sum, 4);
      sum += __shfl_xor(sum, 8);
      float vm = clamp01(vmask[tg]);
      float inv = vm / sum;
      float rs = resid[tg];
#pragma unroll
      for (int n = 0; n < 4; ++n) {
        float a = e[n] * inv;
        attn_lds[tl * 65 + n * 16 + lf] = a;
        s0p[n] += a; s1p[n] += a * rs; s2p[n] += a * rs * rs;
      }
    }
  }
#pragma unroll
  for (int n = 0; n < 4; ++n) {
    s0p[n] += __shfl_xor(s0p[n], 16); s0p[n] += __shfl_xor(s0p[n], 32);
    s1p[n] += __shfl_xor(s1p[n], 16); s1p[n] += __shfl_xor(s1p[n], 32);
    s2p[n] += __shfl_xor(s2p[n], 16); s2p[n] += __shfl_xor(s2p[n], 32);
  }
  if (hi == 0) {
#pragma unroll
    for (int n = 0; n < 4; ++n) {
      atomicAdd(&s0s[n * 16 + lf], s0p[n]);
      atomicAdd(&s1s[n * 16 + lf], s1p[n]);
      atomicAdd(&s2s[n * 16 + lf], s2p[n]);
    }
  }
  __syncthreads();
#pragma unroll
  for (int it = 0; it < 16; ++it) {
    int ci = it * 256 + tid;
    int tl = ci >> 4, c4 = (ci & 15) * 4;
    float4 val;
    val.x = attn_lds[tl * 65 + c4];
    val.y = attn_lds[tl * 65 + c4 + 1];
    val.z = attn_lds[tl * 65 + c4 + 2];
    val.w = attn_lds[tl * 65 + c4 + 3];
    *reinterpret_cast<float4*>(&attn[(size_t)(base + tl) * 64 + c4]) = val;
  }
  if (tid < 64) {
    atomicAdd(&S0[bq * 64 + tid], s0s[tid]);
    atomicAdd(&S1[bq * 64 + tid], s1s[tid]);
    atomicAdd(&S2[bq * 64 + tid], s2s[tid]);
  }
}

// ---------------------------------------------------------------------------
// 8. role statistics finalize
// ---------------------------------------------------------------------------
__global__ __launch_bounds__(64) void role_kernel(
    const float* __restrict__ S0, const float* __restrict__ S1,
    const float* __restrict__ S2, const float* __restrict__ sup,
    float* __restrict__ out, float* __restrict__ rv) {
  int b = blockIdx.x, m = threadIdx.x;
  float mass = S0[b * 64 + m], s1 = S1[b * 64 + m], s2 = S2[b * 64 + m];
  float dn = fmaxf(mass, 1e-6f);
  float v = s1 / dn;
  float var = (s2 - 2.f * v * s1 + v * v * mass) / dn;
  var = fmaxf(var, 1e-4f);
  float support = fmaxf(sup[b], 1.f);
  float cov = fmaxf(mass / support, 0.05f);
  out[OUT_RV + b * 64 + m] = v;
  out[OUT_VAR + b * 64 + m] = var;
  out[OUT_COV + b * 64 + m] = cov;
  rv[b * 64 + m] = v;
}

// ---------------------------------------------------------------------------
// 9. summary MLP
// ---------------------------------------------------------------------------
__global__ __launch_bounds__(512) void mlp_kernel(
    const float* __restrict__ Sh, const float* __restrict__ Sh2,
    const float* __restrict__ spc, const float* __restrict__ sup,
    const float* __restrict__ Wp1, const float* __restrict__ bp1,
    const float* __restrict__ Wp2, const float* __restrict__ bp2,
    float* __restrict__ out) {
  int b = blockIdx.x, j = threadIdx.x;
  __shared__ float ms[1024];
  __shared__ float zg[512];
  float denom = fmaxf(spc[b], 1.0f);
  float mean = Sh[b * 512 + j] / denom;
  float ex2 = Sh2[b * 512 + j] / denom;
  float var = fmaxf(ex2 - mean * mean, 0.f);
  ms[j] = mean;
  ms[512 + j] = sqrtf(var + 1e-6f);
  __syncthreads();
  float z = bp1[j];
  for (int k = 0; k < 1024; ++k) z = fmaf(ms[k], Wp1[k * 512 + j], z);
  zg[j] = gelu_f(z);
  __syncthreads();
  float o = bp2[j];
  for (int k = 0; k < 512; ++k) o = fmaf(zg[k], Wp2[k * 512 + j], o);
  float sm = tanhf(o);
  out[OUT_SUM + b * 512 + j] = (sup[b] > 0.f) ? sm : 0.f;
}

// ---------------------------------------------------------------------------
// 10. prompt_role_fit
// ---------------------------------------------------------------------------
__global__ __launch_bounds__(256) void fit_kernel(
    const float* __restrict__ attn, const float* __restrict__ rv,
    const float* __restrict__ vmask, float* __restrict__ out) {
  int tid = threadIdx.x;
  int wv = tid >> 6, lane = tid & 63;
  int t = blockIdx.x * 4 + wv;
  int b = t >> 11;
  float a = attn[(size_t)t * 64 + lane] * rv[b * 64 + lane];
  for (int o = 32; o > 0; o >>= 1) a += __shfl_xor(a, o);
  if (lane == 0) out[OUT_FIT + t] = a * clamp01(vmask[t]);
}

// ---------------------------------------------------------------------------
extern "C" void kernel_launch(void* const* d_in, const int* in_sizes, int n_in,
                              void* d_out, int out_size, void* d_ws, size_t ws_size,
                              hipStream_t stream) {
  (void)in_sizes; (void)n_in; (void)out_size; (void)ws_size;
  const int* units = (const int*)d_in[0];
  const float* dur = (const float*)d_in[1];
  const float* vmask = (const float*)d_in[2];
  const float* smask = (const float*)d_in[3];
  const float* emb = (const float*)d_in[4];
  const float* W_in = (const float*)d_in[5];
  const float* b_in = (const float*)d_in[6];
  const float* W_c1 = (const float*)d_in[7];
  const float* b_c1 = (const float*)d_in[8];
  const float* W_c2 = (const float*)d_in[9];
  const float* b_c2 = (const float*)d_in[10];
  const float* ln_w = (const float*)d_in[11];
  const float* ln_b = (const float*)d_in[12];
  const float* ck = (const float*)d_in[13];
  const float* W_p1 = (const float*)d_in[14];
  const float* b_p1 = (const float*)d_in[15];
  const float* W_p2 = (const float*)d_in[16];
  const float* b_p2 = (const float*)d_in[17];
  float* out = (float*)d_out;

  char* w = (char*)d_ws;
  float* S0 = (float*)(w + OFF_S0);
  float* S1 = (float*)(w + OFF_S1);
  float* S2 = (float*)(w + OFF_S2);
  float* Sh = (float*)(w + OFF_SH);
  float* Sh2 = (float*)(w + OFF_SH2);
  float* resid = (float*)(w + OFF_RESID);
  float* gr = (float*)(w + OFF_GR);
  float* sup = (float*)(w + OFF_SUP);
  float* spc = (float*)(w + OFF_SPC);
  float* rv = (float*)(w + OFF_RVW);
  u16* wtin = (u16*)(w + OFF_WTIN);
  u8* wtc1 = (u8*)(w + OFF_WTC1);
  u8* wtc2 = (u8*)(w + OFF_WTC2);
  u16* ckb = (u16*)(w + OFF_CKB);
  u16* embb = (u16*)(w + OFF_EMBB);
  u16* tbl = (u16*)(w + OFF_TBL);
  u8* h0p = (u8*)(w + OFF_H0);   // fp8 x64, padded [B][TP][D]
  u8* h1p = (u8*)(w + OFF_H1);   // fp8 x64, padded [B][TP][D]
  u16* h2 = (u16*)(w + OFF_H2);  // bf16 final h [B][T][D]
  float* attn = (float*)(w + OFF_ATTN);

  hipMemsetAsync(d_ws, 0, ZERO_BYTES, stream);
  median_kernel<<<B_, 256, 0, stream>>>(dur, vmask, smask, out, gr, sup, spc, resid);
  wpack_kernel<<<448, 256, 0, stream>>>(W_in, W_c1, W_c2, wtin, wtc1, wtc2);
  convert_kernel<<<2080, 256, 0, stream>>>(ck, emb, ckb, embb);
  gemm_plain_kernel<<<dim3(64, 4), 256, 0, stream>>>(embb, wtin, b_in, tbl);
  gather_kernel<<<B_ * TP_ / 4, 256, 0, stream>>>(units, resid, vmask, smask, tbl,
                                                  W_in + 512 * 512, W_in + 513 * 512, h0p, h1p);
  conv_gemm_kernel<1, 1><<<4096, 256, 0, stream>>>(h0p, wtc1, b_c1, (void*)h1p);
  conv_gemm_kernel<0, 0><<<4096, 256, 0, stream>>>(h1p, wtc2, b_c2, (void*)h2);
  lnpool_kernel<<<dim3(16, 32), 256, 0, stream>>>(h2, ln_w, ln_b, vmask, smask, Sh, Sh2);
  score_kernel<<<256, 256, 0, stream>>>(h2, ckb, resid, vmask, attn, S0, S1, S2);
  role_kernel<<<B_, 64, 0, stream>>>(S0, S1, S2, sup, out, rv);
  mlp_kernel<<<B_, 512, 0, stream>>>(Sh, Sh2, spc, sup, W_p1, b_p1, W_p2, b_p2, out);
  fit_kernel<<<B_ * T_ / 4, 256, 0, stream>>>(attn, rv, vmask, out);
}

// Round 12
// 298.562 us; speedup vs baseline: 1.6786x; 1.6786x over previous
//
#include <hip/hip_runtime.h>
#include <hip/hip_bf16.h>
#include <math.h>

// ---------------------------------------------------------------------------
// PromptDurationMemoryEncoder — MI355X (gfx950)
// Conv GEMMs: FP8 e4m3 data (x64 scale), MX-scaled K=128 MFMA (unit scales),
// 128x64 tile, 3 blocks/CU (launch_bounds-pinned), shufflevector operands.
// ---------------------------------------------------------------------------

typedef unsigned short u16;
typedef unsigned char u8;
typedef __attribute__((ext_vector_type(8))) short short8;
typedef __attribute__((ext_vector_type(4))) float f32x4;
typedef __attribute__((ext_vector_type(4))) int int4v;
typedef __attribute__((ext_vector_type(8))) int int8v;

constexpr int B_ = 32, T_ = 2048, D_ = 512, V_ = 4096, M_ = 64, TP_ = 2050;

// output offsets (floats)
constexpr int OUT_GR = 0;          // [32]
constexpr int OUT_SUM = 32;        // [32*512]
constexpr int OUT_RV = 16416;      // [32*64]
constexpr int OUT_VAR = 18464;     // [32*64]
constexpr int OUT_COV = 20512;     // [32*64]
constexpr int OUT_FIT = 22560;     // [32*2048]

// workspace byte offsets
constexpr size_t OFF_S0 = 0;
constexpr size_t OFF_S1 = OFF_S0 + 2048 * 4;
constexpr size_t OFF_S2 = OFF_S1 + 2048 * 4;
constexpr size_t OFF_SH = OFF_S2 + 2048 * 4;          // 16384 f32
constexpr size_t OFF_SH2 = OFF_SH + 16384 * 4;
constexpr size_t ZERO_BYTES = OFF_SH2 + 16384 * 4;    // 155648
constexpr size_t OFF_RESID = ZERO_BYTES;              // 65536 f32
constexpr size_t OFF_GR = OFF_RESID + 65536 * 4;
constexpr size_t OFF_SUP = OFF_GR + 128;
constexpr size_t OFF_SPC = OFF_SUP + 128;
constexpr size_t OFF_RVW = OFF_SPC + 128;             // 2048 f32
constexpr size_t OFF_WTIN = OFF_RVW + 8192;           // 512*512 bf16
constexpr size_t OFF_WTC1 = OFF_WTIN + 524288;        // 3*512*512 fp8
constexpr size_t OFF_WTC2 = OFF_WTC1 + 786432;        // 3*512*512 fp8
constexpr size_t OFF_CKB = OFF_WTC2 + 786432;         // 64*512 bf16
constexpr size_t OFF_EMBB = OFF_CKB + 65536;          // 4096*512 bf16
constexpr size_t OFF_TBL = OFF_EMBB + 4194304;        // 4096*512 bf16 (slot sized f32)
constexpr size_t OFF_H0 = OFF_TBL + 8388608;          // B*TP*D fp8 (x64 scale)
constexpr size_t OFF_H1 = OFF_H0 + 33587200;          // B*TP*D fp8 (x64 scale)
constexpr size_t OFF_H2 = OFF_H1 + 33587200;          // B*T*D bf16 (final h)
constexpr size_t OFF_ATTN = OFF_H2 + 67108864;        // 65536*64 f32

__device__ __forceinline__ float clamp01(float x) { return fminf(fmaxf(x, 0.f), 1.f); }
__device__ __forceinline__ float b2f(u16 u) { return __uint_as_float(((unsigned)u) << 16); }
__device__ __forceinline__ u16 f2b(float f) {
  unsigned u = __float_as_uint(f);
  unsigned r = (u + 0x7FFFu + ((u >> 16) & 1u)) >> 16;
  return (u16)r;
}
__device__ __forceinline__ u8 f2fp8(float f) {
  return (u8)(__builtin_amdgcn_cvt_pk_fp8_f32(f, f, 0, false) & 0xFF);
}
__device__ __forceinline__ float gelu_f(float x) {
  return 0.5f * x * (1.0f + erff(x * 0.7071067811865475f));
}
__device__ __forceinline__ void gload16(const void* g, void* l) {
  __builtin_amdgcn_global_load_lds((const __attribute__((address_space(1))) void*)g,
                                   (__attribute__((address_space(3))) void*)l, 16, 0, 0);
}

// ---------------------------------------------------------------------------
// 1. median + residual + support counts (register keys, wave-shfl reduce)
// ---------------------------------------------------------------------------
__global__ __launch_bounds__(256) void median_kernel(
    const float* __restrict__ dur, const float* __restrict__ vmask,
    const float* __restrict__ smask, float* __restrict__ out0,
    float* __restrict__ gr, float* __restrict__ sup, float* __restrict__ spc,
    float* __restrict__ resid) {
  int b = blockIdx.x, tid = threadIdx.x;
  int wv = tid >> 6, lane = tid & 63;
  __shared__ float wredf[8];
  __shared__ int wredi[4];
  unsigned keys[8];
  float ldv[8], vmv[8];
  float vs = 0.f, ss = 0.f;
#pragma unroll
  for (int j = 0; j < 8; ++j) {
    int t = j * 256 + tid;
    float vm = clamp01(vmask[b * T_ + t]);
    float sm = clamp01(smask[b * T_ + t]) * vm;
    vs += vm; ss += sm;
    float ld = logf(fmaxf(dur[b * T_ + t], 1e-4f)) * vm;
    ldv[j] = ld; vmv[j] = vm;
    unsigned bits = __float_as_uint(ld);
    unsigned key = (bits & 0x80000000u) ? ~bits : (bits | 0x80000000u);
    keys[j] = (sm > 0.5f) ? key : 0xFFFFFFFFu;
  }
  for (int o = 32; o > 0; o >>= 1) { vs += __shfl_xor(vs, o); ss += __shfl_xor(ss, o); }
  if (lane == 0) { wredf[wv] = vs; wredf[4 + wv] = ss; }
  __syncthreads();
  float s_sup = wredf[0] + wredf[1] + wredf[2] + wredf[3];
  float s_spc = wredf[4] + wredf[5] + wredf[6] + wredf[7];
  int n = (int)(s_spc + 0.5f);
  int target = (n > 0) ? ((n - 1) / 2 + 1) : 1;
  unsigned lo = 0u, hi = 0xFFFFFFFFu;
  for (int it = 0; it < 32; ++it) {
    unsigned mid = lo + ((hi - lo) >> 1);
    int c = 0;
#pragma unroll
    for (int j = 0; j < 8; ++j) c += (keys[j] <= mid) ? 1 : 0;
    for (int o = 32; o > 0; o >>= 1) c += __shfl_xor(c, o);
    __syncthreads();
    if (lane == 0) wredi[wv] = c;
    __syncthreads();
    int tot = wredi[0] + wredi[1] + wredi[2] + wredi[3];
    if (tot >= target) hi = mid; else lo = mid + 1;
  }
  float med = 0.f;
  if (n > 0) {
    unsigned K = lo;
    unsigned ub = (K & 0x80000000u) ? (K & 0x7FFFFFFFu) : ~K;
    med = __uint_as_float(ub);
  }
  if (tid == 0) { out0[OUT_GR + b] = med; gr[b] = med; sup[b] = s_sup; spc[b] = s_spc; }
#pragma unroll
  for (int j = 0; j < 8; ++j) {
    int t = j * 256 + tid;
    resid[b * T_ + t] = (ldv[j] - med) * vmv[j];
  }
}

// ---------------------------------------------------------------------------
// 2a. weight transpose: W_in -> bf16; W_c1/W_c2 -> fp8 e4m3 (x64 scale)
// ---------------------------------------------------------------------------
__global__ __launch_bounds__(256) void wpack_kernel(
    const float* __restrict__ W_in, const float* __restrict__ W_c1,
    const float* __restrict__ W_c2, u16* __restrict__ wtin,
    u8* __restrict__ wtc1, u8* __restrict__ wtc2) {
  __shared__ float tile[64][65];
  int x = blockIdx.x;        // 0..447
  int m = x >> 6, tl = x & 63;
  int kt = tl >> 3, nt = tl & 7;
  const float* src;
  if (m == 0) src = W_in;
  else if (m <= 3) src = W_c1 + (size_t)(m - 1) * 262144;
  else src = W_c2 + (size_t)(m - 4) * 262144;
  int tid = threadIdx.x;
#pragma unroll
  for (int j = 0; j < 16; ++j) {
    int idx = j * 256 + tid;
    int r = idx >> 6, c = idx & 63;
    tile[r][c] = src[(size_t)(kt * 64 + r) * 512 + nt * 64 + c];
  }
  __syncthreads();
  if (m == 0) {
#pragma unroll
    for (int j = 0; j < 16; ++j) {
      int idx = j * 256 + tid;
      int r = idx >> 6, c = idx & 63;
      wtin[(size_t)(nt * 64 + r) * 512 + kt * 64 + c] = f2b(tile[c][r]);
    }
  } else {
    u8* dst = (m <= 3) ? wtc1 + (size_t)(m - 1) * 262144
                       : wtc2 + (size_t)(m - 4) * 262144;
#pragma unroll
    for (int j = 0; j < 16; ++j) {
      int idx = j * 256 + tid;
      int r = idx >> 6, c = idx & 63;
      dst[(size_t)(nt * 64 + r) * 512 + kt * 64 + c] = f2fp8(tile[c][r] * 64.f);
    }
  }
}

// ---------------------------------------------------------------------------
// 2b. straight f32 -> bf16 convert for ck (32768) and emb (2097152)
// ---------------------------------------------------------------------------
__global__ __launch_bounds__(256) void convert_kernel(
    const float* __restrict__ ck, const float* __restrict__ emb,
    u16* __restrict__ ckb, u16* __restrict__ embb) {
  int idx = blockIdx.x * 256 + threadIdx.x;   // one per 4 elements; 532480 total
  float4 v;
  u16* dst;
  if (idx < 8192) {
    v = reinterpret_cast<const float4*>(ck)[idx];
    dst = ckb + idx * 4;
  } else {
    int i = idx - 8192;
    v = reinterpret_cast<const float4*>(emb)[i];
    dst = embb + (size_t)i * 4;
  }
  uint2 o;
  o.x = (unsigned)f2b(v.x) | ((unsigned)f2b(v.y) << 16);
  o.y = (unsigned)f2b(v.z) | ((unsigned)f2b(v.w) << 16);
  *reinterpret_cast<uint2*>(dst) = o;
}

// ---------------------------------------------------------------------------
// 3a. plain MFMA GEMM (tbl = emb @ W_in): 64x128 tile -> 256 blocks, bf16 out
// ---------------------------------------------------------------------------
__global__ __launch_bounds__(256) void gemm_plain_kernel(
    const u16* __restrict__ A, const u16* __restrict__ Bt,
    const float* __restrict__ bias, u16* __restrict__ Cout) {
  __shared__ u16 ldsA[64 * 64];
  __shared__ u16 ldsB[128 * 64];
  const int tid = threadIdx.x;
  const int row0 = blockIdx.x * 64;
  const int col0 = blockIdx.y * 128;

  f32x4 acc[2][4] = {};
  const int wv = tid >> 6, lane = tid & 63;
  const int wr = (wv >> 1) << 5;           // 0,32
  const int wc = (wv & 1) << 6;            // 0,64
  const int lr = lane & 15, cgrp = lane >> 4;

  const u16* Ab = A + (size_t)row0 * 512;
  const u16* Bb = Bt + (size_t)col0 * 512;
  for (int k0 = 0; k0 < 512; k0 += 64) {
    if (k0) __syncthreads();
#pragma unroll
    for (int j = 0; j < 2; ++j) {
      int ci = j * 256 + tid;
      int r = ci >> 3, s = ci & 7;
      int gs = s ^ (r & 7);
      gload16(Ab + (size_t)r * 512 + k0 + gs * 8, &ldsA[ci * 8]);
    }
#pragma unroll
    for (int j = 0; j < 4; ++j) {
      int ci = j * 256 + tid;
      int r = ci >> 3, s = ci & 7;
      int gs = s ^ (r & 7);
      gload16(Bb + (size_t)r * 512 + k0 + gs * 8, &ldsB[ci * 8]);
    }
    __syncthreads();
#pragma unroll
    for (int kk = 0; kk < 2; ++kk) {
      short8 af[2], bfr[4];
#pragma unroll
      for (int m = 0; m < 2; ++m) {
        int r = wr + m * 16 + lr;
        int s = (kk * 4 + cgrp) ^ (r & 7);
        af[m] = *reinterpret_cast<const short8*>(&ldsA[(r << 6) + (s << 3)]);
      }
#pragma unroll
      for (int n = 0; n < 4; ++n) {
        int r = wc + n * 16 + lr;
        int s = (kk * 4 + cgrp) ^ (r & 7);
        bfr[n] = *reinterpret_cast<const short8*>(&ldsB[(r << 6) + (s << 3)]);
      }
#pragma unroll
      for (int m = 0; m < 2; ++m)
#pragma unroll
        for (int n = 0; n < 4; ++n)
          acc[m][n] = __builtin_amdgcn_mfma_f32_16x16x32_bf16(af[m], bfr[n], acc[m][n], 0, 0, 0);
    }
  }
#pragma unroll
  for (int m = 0; m < 2; ++m)
#pragma unroll
    for (int n = 0; n < 4; ++n)
#pragma unroll
      for (int r = 0; r < 4; ++r) {
        int lrow = wr + m * 16 + (lane >> 4) * 4 + r;
        int lcol = wc + n * 16 + (lane & 15);
        Cout[(size_t)(row0 + lrow) * 512 + col0 + lcol] =
            f2b(acc[m][n][r] + bias[col0 + lcol]);
      }
}

// ---------------------------------------------------------------------------
// 3b. tap-fused conv GEMM in FP8 — 128x64 tile, MX-scaled K=128 MFMA.
//     Operands built via shufflevector (no scalar inserts -> no spills);
//     __launch_bounds__(256,3) pins 3 blocks/CU; k0 loop not unrolled.
// ---------------------------------------------------------------------------
template <int PADOUT, int OUTFP8>
__global__ __launch_bounds__(256, 3) void conv_gemm_kernel(
    const u8* __restrict__ A, const u8* __restrict__ Bt,
    const float* __restrict__ bias, void* __restrict__ Cout) {
  __shared__ u8 ldsA[130 * 128];             // 16.6 KB
  __shared__ u8 ldsB[3 * 64 * 128];          // 24 KB
  const int tid = threadIdx.x;
  const int id = blockIdx.x;                 // 0..4095
  const int wg = (id & 7) * 512 + (id >> 3); // XCD swizzle
  const int rb = wg >> 3, cb = wg & 7;
  const int row0 = rb * 128, col0 = cb * 64;
  const int b = row0 >> 11, t0 = row0 & 2047;
  const size_t aBase = ((size_t)b * TP_ + t0) * 512;
  const size_t oBase = PADOUT ? ((size_t)b * TP_ + 1 + t0) : (size_t)row0;

  f32x4 acc[4][2] = {};
  const int wv = tid >> 6, lane = tid & 63;
  const int wr = (wv >> 1) << 6;             // 0,64
  const int wc = (wv & 1) << 5;              // 0,32
  const int lr = lane & 15, cgrp = lane >> 4;

  const u8* Ab = A + aBase;
#pragma unroll 1
  for (int k0 = 0; k0 < 512; k0 += 128) {
    if (k0) __syncthreads();
    // stage A window: 130 rows x 8 16B-chunks = 1040
#pragma unroll
    for (int j = 0; j < 5; ++j) {
      int ci = j * 256 + tid;
      if (ci < 1040) {
        int r = ci >> 3, s = ci & 7;
        int gs = s ^ (r & 7);
        gload16(Ab + (size_t)r * 512 + k0 + gs * 16, &ldsA[ci * 16]);
      }
    }
    // stage B: 3 taps x 64 cols x 8 chunks = 1536
#pragma unroll
    for (int j = 0; j < 6; ++j) {
      int ci = j * 256 + tid;
      int r = ci >> 3, s = ci & 7;           // r = tap*64 + n (0..191)
      int tap = r >> 6, n = r & 63;
      int gs = s ^ (r & 7);
      gload16(Bt + ((size_t)(tap * 512 + col0 + n)) * 512 + k0 + gs * 16, &ldsB[ci * 16]);
    }
    __syncthreads();
#pragma unroll
    for (int tap = 0; tap < 3; ++tap) {
      int8v af[4], bfr[2];
#pragma unroll
      for (int m = 0; m < 4; ++m) {
        int r = wr + m * 16 + lr + tap;      // window row 0..129
        int s0 = (2 * cgrp) ^ (r & 7);
        int s1 = (2 * cgrp + 1) ^ (r & 7);
        int4v lo = *reinterpret_cast<const int4v*>(&ldsA[(r << 7) + (s0 << 4)]);
        int4v hi = *reinterpret_cast<const int4v*>(&ldsA[(r << 7) + (s1 << 4)]);
        af[m] = __builtin_shufflevector(lo, hi, 0, 1, 2, 3, 4, 5, 6, 7);
      }
#pragma unroll
      for (int n = 0; n < 2; ++n) {
        int rB = tap * 64 + wc + n * 16 + lr;
        int s0 = (2 * cgrp) ^ (rB & 7);
        int s1 = (2 * cgrp + 1) ^ (rB & 7);
        int4v lo = *reinterpret_cast<const int4v*>(&ldsB[(rB << 7) + (s0 << 4)]);
        int4v hi = *reinterpret_cast<const int4v*>(&ldsB[(rB << 7) + (s1 << 4)]);
        bfr[n] = __builtin_shufflevector(lo, hi, 0, 1, 2, 3, 4, 5, 6, 7);
      }
#pragma unroll
      for (int m = 0; m < 4; ++m)
#pragma unroll
        for (int n = 0; n < 2; ++n)
          acc[m][n] = __builtin_amdgcn_mfma_scale_f32_16x16x128_f8f6f4(
              af[m], bfr[n], acc[m][n], 0, 0, 0, 0x7F7F7F7F, 0, 0x7F7F7F7F);
    }
  }
  // epilogue: C/D layout col=lane&15, row=(lane>>4)*4+reg
#pragma unroll
  for (int m = 0; m < 4; ++m)
#pragma unroll
    for (int n = 0; n < 2; ++n)
#pragma unroll
      for (int r = 0; r < 4; ++r) {
        int lrow = wr + m * 16 + (lane >> 4) * 4 + r;
        int lcol = wc + n * 16 + (lane & 15);
        float v = acc[m][n][r] * (1.f / 4096.f) + bias[col0 + lcol];
        v = gelu_f(v);
        if (OUTFP8)
          ((u8*)Cout)[(oBase + lrow) * 512 + col0 + lcol] = f2fp8(v * 64.f);
        else
          ((u16*)Cout)[(oBase + lrow) * 512 + col0 + lcol] = f2b(v);
      }
}

// ---------------------------------------------------------------------------
// 4. gather: h0[b,t] = fp8( (tbl[unit] + resid*W_in[512] + sil*W_in[513]) * 64 )
// ---------------------------------------------------------------------------
__global__ __launch_bounds__(256) void gather_kernel(
    const int* __restrict__ units, const float* __restrict__ resid,
    const float* __restrict__ vmask, const float* __restrict__ smask,
    const u16* __restrict__ tbl, const float* __restrict__ w512,
    const float* __restrict__ w513, u8* __restrict__ h0p, u8* __restrict__ h1p) {
  int row = blockIdx.x * 4 + (threadIdx.x >> 6);  // 0..B*TP-1
  int b = row / TP_, tp = row - b * TP_;
  int lane = threadIdx.x & 63;
  size_t o = (size_t)row * 512 + lane * 8;
  if (tp == 0 || tp == TP_ - 1) {
    uint2 z = {0, 0};
    *reinterpret_cast<uint2*>(&h0p[o]) = z;
    *reinterpret_cast<uint2*>(&h1p[o]) = z;
    return;
  }
  int t = tp - 1, g = b * T_ + t;
  float vm = clamp01(vmask[g]);
  float sm = clamp01(smask[g]) * vm;
  float sil = fmaxf(vm - sm, 0.f);
  float rs = resid[g];
  int u = units[g];
  uint4 tv = *reinterpret_cast<const uint4*>(tbl + (size_t)u * 512 + lane * 8);
  float tr[8];
  tr[0] = __uint_as_float(tv.x << 16); tr[1] = __uint_as_float(tv.x & 0xFFFF0000u);
  tr[2] = __uint_as_float(tv.y << 16); tr[3] = __uint_as_float(tv.y & 0xFFFF0000u);
  tr[4] = __uint_as_float(tv.z << 16); tr[5] = __uint_as_float(tv.z & 0xFFFF0000u);
  tr[6] = __uint_as_float(tv.w << 16); tr[7] = __uint_as_float(tv.w & 0xFFFF0000u);
  const float* a = w512 + lane * 8;
  const float* c = w513 + lane * 8;
  float f[8];
#pragma unroll
  for (int j = 0; j < 8; ++j) f[j] = (tr[j] + rs * a[j] + sil * c[j]) * 64.f;
  unsigned lo = __builtin_amdgcn_cvt_pk_fp8_f32(f[0], f[1], 0, false);
  lo = __builtin_amdgcn_cvt_pk_fp8_f32(f[2], f[3], lo, true);
  unsigned hi = __builtin_amdgcn_cvt_pk_fp8_f32(f[4], f[5], 0, false);
  hi = __builtin_amdgcn_cvt_pk_fp8_f32(f[6], f[7], hi, true);
  uint2 val = {lo, hi};
  *reinterpret_cast<uint2*>(&h0p[o]) = val;
}

// ---------------------------------------------------------------------------
// 5. fused LayerNorm (in-place, * valid) + speech-masked pooling sums
// ---------------------------------------------------------------------------
__global__ __launch_bounds__(256) void lnpool_kernel(
    u16* __restrict__ h, const float* __restrict__ lnw,
    const float* __restrict__ lnb, const float* __restrict__ vmask,
    const float* __restrict__ smask, float* __restrict__ Sh,
    float* __restrict__ Sh2) {
  int b = blockIdx.y, chunk = blockIdx.x, tid = threadIdx.x;
  int lane = tid & 63, tof = tid >> 6;
  __shared__ float shA[512], shQ[512];
  shA[tid] = 0.f; shA[tid + 256] = 0.f;
  shQ[tid] = 0.f; shQ[tid + 256] = 0.f;
  __syncthreads();
  int d8 = lane * 8;
  float wv_[8], bv_[8];
#pragma unroll
  for (int j = 0; j < 8; ++j) { wv_[j] = lnw[d8 + j]; bv_[j] = lnb[d8 + j]; }
  float a[8] = {}, q[8] = {};
  for (int i = 0; i < 32; ++i) {
    int t = chunk * 128 + i * 4 + tof;
    int g = b * T_ + t;
    float vm = clamp01(vmask[g]);
    float sp = clamp01(smask[g]) * vm;
    u16* p = h + (size_t)g * 512 + d8;
    uint4 raw = *reinterpret_cast<const uint4*>(p);
    float x[8];
    x[0] = __uint_as_float(raw.x << 16); x[1] = __uint_as_float(raw.x & 0xFFFF0000u);
    x[2] = __uint_as_float(raw.y << 16); x[3] = __uint_as_float(raw.y & 0xFFFF0000u);
    x[4] = __uint_as_float(raw.z << 16); x[5] = __uint_as_float(raw.z & 0xFFFF0000u);
    x[6] = __uint_as_float(raw.w << 16); x[7] = __uint_as_float(raw.w & 0xFFFF0000u);
    float s = 0.f, sq = 0.f;
#pragma unroll
    for (int j = 0; j < 8; ++j) { s += x[j]; sq = fmaf(x[j], x[j], sq); }
    for (int o = 32; o > 0; o >>= 1) { s += __shfl_xor(s, o); sq += __shfl_xor(sq, o); }
    float mu = s * (1.f / 512.f);
    float var = fmaxf(sq * (1.f / 512.f) - mu * mu, 0.f);
    float rstd = rsqrtf(var + 1e-5f);
    u16 ob[8];
#pragma unroll
    for (int j = 0; j < 8; ++j) {
      float y = (x[j] - mu) * rstd * wv_[j] + bv_[j];
      ob[j] = f2b(y * vm);
      float yr = b2f(ob[j]);
      a[j] = fmaf(yr, sp, a[j]);
      q[j] = fmaf(yr * yr, sp, q[j]);
    }
    uint4 val;
    val.x = (unsigned)ob[0] | ((unsigned)ob[1] << 16);
    val.y = (unsigned)ob[2] | ((unsigned)ob[3] << 16);
    val.z = (unsigned)ob[4] | ((unsigned)ob[5] << 16);
    val.w = (unsigned)ob[6] | ((unsigned)ob[7] << 16);
    *reinterpret_cast<uint4*>(p) = val;
  }
#pragma unroll
  for (int j = 0; j < 8; ++j) {
    atomicAdd(&shA[d8 + j], a[j]);
    atomicAdd(&shQ[d8 + j], q[j]);
  }
  __syncthreads();
  atomicAdd(&Sh[b * 512 + tid], shA[tid]);
  atomicAdd(&Sh[b * 512 + tid + 256], shA[tid + 256]);
  atomicAdd(&Sh2[b * 512 + tid], shQ[tid]);
  atomicAdd(&Sh2[b * 512 + tid + 256], shQ[tid + 256]);
}

// ---------------------------------------------------------------------------
// 6. score: MFMA h@ck^T + softmax + attn store + role moments
// ---------------------------------------------------------------------------
__global__ __launch_bounds__(256) void score_kernel(
    const u16* __restrict__ h, const u16* __restrict__ ckb,
    const float* __restrict__ resid, const float* __restrict__ vmask,
    float* __restrict__ attn, float* __restrict__ S0, float* __restrict__ S1,
    float* __restrict__ S2) {
  __shared__ char smem[98304];           // ckl 64KB | ldsH 32KB ; reused as attn_lds
  __shared__ float s0s[64], s1s[64], s2s[64];
  u16* ckl = (u16*)smem;                 // [64 roles][512 k] swizzled
  u16* ldsH = (u16*)(smem + 65536);      // [256 rows][64 k] swizzled
  float* attn_lds = (float*)smem;        // [256][65] after compute

  const int tid = threadIdx.x;
  const int base = blockIdx.x * 256;     // global token base
  const int bq = base >> 11;             // batch index

#pragma unroll
  for (int it = 0; it < 16; ++it) {
    int ci = it * 256 + tid;             // 0..4095 (16B chunks)
    int m = ci >> 6, s = ci & 63;
    int sw = (s & 56) | ((s & 7) ^ (m & 7));
    *reinterpret_cast<uint4*>(&ckl[(m << 9) + (sw << 3)]) =
        *reinterpret_cast<const uint4*>(&ckb[(m << 9) + (s << 3)]);
  }
  if (tid < 64) { s0s[tid] = 0.f; s1s[tid] = 0.f; s2s[tid] = 0.f; }

  const int wv = tid >> 6, lane = tid & 63;
  const int lr = lane & 15, cgrp = lane >> 4;
  const int hi = lane >> 4, lf = lane & 15;
  f32x4 acc[4][4] = {};

  const u16* hb = h + (size_t)base * 512;
  for (int k0 = 0; k0 < 512; k0 += 64) {
    __syncthreads();
#pragma unroll
    for (int j = 0; j < 8; ++j) {
      int ci = j * 256 + tid;
      int r = ci >> 3, s = ci & 7;
      int gs = s ^ (r & 7);
      gload16(hb + (size_t)r * 512 + k0 + gs * 8, &ldsH[ci * 8]);
    }
    __syncthreads();
#pragma unroll
    for (int kk = 0; kk < 2; ++kk) {
      short8 af[4], bfr[4];
#pragma unroll
      for (int m = 0; m < 4; ++m) {
        int r = wv * 64 + m * 16 + lr;
        int s = (kk * 4 + cgrp) ^ (r & 7);
        af[m] = *reinterpret_cast<const short8*>(&ldsH[(r << 6) + (s << 3)]);
      }
#pragma unroll
      for (int n = 0; n < 4; ++n) {
        int r = n * 16 + lr;
        int s = (kk * 4 + cgrp) ^ (r & 7);
        bfr[n] = *reinterpret_cast<const short8*>(&ckl[(r << 9) + k0 + (s << 3)]);
      }
#pragma unroll
      for (int m = 0; m < 4; ++m)
#pragma unroll
        for (int n = 0; n < 4; ++n)
          acc[m][n] = __builtin_amdgcn_mfma_f32_16x16x32_bf16(af[m], bfr[n], acc[m][n], 0, 0, 0);
    }
  }
  __syncthreads();

  const float scale = 0.04419417382415922f;  // 1/sqrt(512)
  float s0p[4] = {0.f, 0.f, 0.f, 0.f};
  float s1p[4] = {0.f, 0.f, 0.f, 0.f};
  float s2p[4] = {0.f, 0.f, 0.f, 0.f};
#pragma unroll
  for (int m = 0; m < 4; ++m) {
#pragma unroll
    for (int rr = 0; rr < 4; ++rr) {
      int tl = wv * 64 + m * 16 + hi * 4 + rr;
      int tg = base + tl;
      float v[4];
#pragma unroll
      for (int n = 0; n < 4; ++n) v[n] = acc[m][n][rr] * scale;
      float mx = fmaxf(fmaxf(v[0], v[1]), fmaxf(v[2], v[3]));
      mx = fmaxf(mx, __shfl_xor(mx, 1));
      mx = fmaxf(mx, __shfl_xor(mx, 2));
      mx = fmaxf(mx, __shfl_xor(mx, 4));
      mx = fmaxf(mx, __shfl_xor(mx, 8));
      float e[4], sum = 0.f;
#pragma unroll
      for (int n = 0; n < 4; ++n) { e[n] = expf(v[n] - mx); sum += e[n]; }
      sum += __shfl_xor(sum, 1);
      sum += __shfl_xor(sum, 2);
      sum += __shfl_xor(sum, 4);
      sum += __shfl_xor(sum, 8);
      float vm = clamp01(vmask[tg]);
      float inv = vm / sum;
      float rs = resid[tg];
#pragma unroll
      for (int n = 0; n < 4; ++n) {
        float a = e[n] * inv;
        attn_lds[tl * 65 + n * 16 + lf] = a;
        s0p[n] += a; s1p[n] += a * rs; s2p[n] += a * rs * rs;
      }
    }
  }
#pragma unroll
  for (int n = 0; n < 4; ++n) {
    s0p[n] += __shfl_xor(s0p[n], 16); s0p[n] += __shfl_xor(s0p[n], 32);
    s1p[n] += __shfl_xor(s1p[n], 16); s1p[n] += __shfl_xor(s1p[n], 32);
    s2p[n] += __shfl_xor(s2p[n], 16); s2p[n] += __shfl_xor(s2p[n], 32);
  }
  if (hi == 0) {
#pragma unroll
    for (int n = 0; n < 4; ++n) {
      atomicAdd(&s0s[n * 16 + lf], s0p[n]);
      atomicAdd(&s1s[n * 16 + lf], s1p[n]);
      atomicAdd(&s2s[n * 16 + lf], s2p[n]);
    }
  }
  __syncthreads();
#pragma unroll
  for (int it = 0; it < 16; ++it) {
    int ci = it * 256 + tid;
    int tl = ci >> 4, c4 = (ci & 15) * 4;
    float4 val;
    val.x = attn_lds[tl * 65 + c4];
    val.y = attn_lds[tl * 65 + c4 + 1];
    val.z = attn_lds[tl * 65 + c4 + 2];
    val.w = attn_lds[tl * 65 + c4 + 3];
    *reinterpret_cast<float4*>(&attn[(size_t)(base + tl) * 64 + c4]) = val;
  }
  if (tid < 64) {
    atomicAdd(&S0[bq * 64 + tid], s0s[tid]);
    atomicAdd(&S1[bq * 64 + tid], s1s[tid]);
    atomicAdd(&S2[bq * 64 + tid], s2s[tid]);
  }
}

// ---------------------------------------------------------------------------
// 8. role statistics finalize
// ---------------------------------------------------------------------------
__global__ __launch_bounds__(64) void role_kernel(
    const float* __restrict__ S0, const float* __restrict__ S1,
    const float* __restrict__ S2, const float* __restrict__ sup,
    float* __restrict__ out, float* __restrict__ rv) {
  int b = blockIdx.x, m = threadIdx.x;
  float mass = S0[b * 64 + m], s1 = S1[b * 64 + m], s2 = S2[b * 64 + m];
  float dn = fmaxf(mass, 1e-6f);
  float v = s1 / dn;
  float var = (s2 - 2.f * v * s1 + v * v * mass) / dn;
  var = fmaxf(var, 1e-4f);
  float support = fmaxf(sup[b], 1.f);
  float cov = fmaxf(mass / support, 0.05f);
  out[OUT_RV + b * 64 + m] = v;
  out[OUT_VAR + b * 64 + m] = var;
  out[OUT_COV + b * 64 + m] = cov;
  rv[b * 64 + m] = v;
}

// ---------------------------------------------------------------------------
// 9. summary MLP
// ---------------------------------------------------------------------------
__global__ __launch_bounds__(512) void mlp_kernel(
    const float* __restrict__ Sh, const float* __restrict__ Sh2,
    const float* __restrict__ spc, const float* __restrict__ sup,
    const float* __restrict__ Wp1, const float* __restrict__ bp1,
    const float* __restrict__ Wp2, const float* __restrict__ bp2,
    float* __restrict__ out) {
  int b = blockIdx.x, j = threadIdx.x;
  __shared__ float ms[1024];
  __shared__ float zg[512];
  float denom = fmaxf(spc[b], 1.0f);
  float mean = Sh[b * 512 + j] / denom;
  float ex2 = Sh2[b * 512 + j] / denom;
  float var = fmaxf(ex2 - mean * mean, 0.f);
  ms[j] = mean;
  ms[512 + j] = sqrtf(var + 1e-6f);
  __syncthreads();
  float z = bp1[j];
  for (int k = 0; k < 1024; ++k) z = fmaf(ms[k], Wp1[k * 512 + j], z);
  zg[j] = gelu_f(z);
  __syncthreads();
  float o = bp2[j];
  for (int k = 0; k < 512; ++k) o = fmaf(zg[k], Wp2[k * 512 + j], o);
  float sm = tanhf(o);
  out[OUT_SUM + b * 512 + j] = (sup[b] > 0.f) ? sm : 0.f;
}

// ---------------------------------------------------------------------------
// 10. prompt_role_fit
// ---------------------------------------------------------------------------
__global__ __launch_bounds__(256) void fit_kernel(
    const float* __restrict__ attn, const float* __restrict__ rv,
    const float* __restrict__ vmask, float* __restrict__ out) {
  int tid = threadIdx.x;
  int wv = tid >> 6, lane = tid & 63;
  int t = blockIdx.x * 4 + wv;
  int b = t >> 11;
  float a = attn[(size_t)t * 64 + lane] * rv[b * 64 + lane];
  for (int o = 32; o > 0; o >>= 1) a += __shfl_xor(a, o);
  if (lane == 0) out[OUT_FIT + t] = a * clamp01(vmask[t]);
}

// ---------------------------------------------------------------------------
extern "C" void kernel_launch(void* const* d_in, const int* in_sizes, int n_in,
                              void* d_out, int out_size, void* d_ws, size_t ws_size,
                              hipStream_t stream) {
  (void)in_sizes; (void)n_in; (void)out_size; (void)ws_size;
  const int* units = (const int*)d_in[0];
  const float* dur = (const float*)d_in[1];
  const float* vmask = (const float*)d_in[2];
  const float* smask = (const float*)d_in[3];
  const float* emb = (const float*)d_in[4];
  const float* W_in = (const float*)d_in[5];
  const float* b_in = (const float*)d_in[6];
  const float* W_c1 = (const float*)d_in[7];
  const float* b_c1 = (const float*)d_in[8];
  const float* W_c2 = (const float*)d_in[9];
  const float* b_c2 = (const float*)d_in[10];
  const float* ln_w = (const float*)d_in[11];
  const float* ln_b = (const float*)d_in[12];
  const float* ck = (const float*)d_in[13];
  const float* W_p1 = (const float*)d_in[14];
  const float* b_p1 = (const float*)d_in[15];
  const float* W_p2 = (const float*)d_in[16];
  const float* b_p2 = (const float*)d_in[17];
  float* out = (float*)d_out;

  char* w = (char*)d_ws;
  float* S0 = (float*)(w + OFF_S0);
  float* S1 = (float*)(w + OFF_S1);
  float* S2 = (float*)(w + OFF_S2);
  float* Sh = (float*)(w + OFF_SH);
  float* Sh2 = (float*)(w + OFF_SH2);
  float* resid = (float*)(w + OFF_RESID);
  float* gr = (float*)(w + OFF_GR);
  float* sup = (float*)(w + OFF_SUP);
  float* spc = (float*)(w + OFF_SPC);
  float* rv = (float*)(w + OFF_RVW);
  u16* wtin = (u16*)(w + OFF_WTIN);
  u8* wtc1 = (u8*)(w + OFF_WTC1);
  u8* wtc2 = (u8*)(w + OFF_WTC2);
  u16* ckb = (u16*)(w + OFF_CKB);
  u16* embb = (u16*)(w + OFF_EMBB);
  u16* tbl = (u16*)(w + OFF_TBL);
  u8* h0p = (u8*)(w + OFF_H0);   // fp8 x64, padded [B][TP][D]
  u8* h1p = (u8*)(w + OFF_H1);   // fp8 x64, padded [B][TP][D]
  u16* h2 = (u16*)(w + OFF_H2);  // bf16 final h [B][T][D]
  float* attn = (float*)(w + OFF_ATTN);

  hipMemsetAsync(d_ws, 0, ZERO_BYTES, stream);
  median_kernel<<<B_, 256, 0, stream>>>(dur, vmask, smask, out, gr, sup, spc, resid);
  wpack_kernel<<<448, 256, 0, stream>>>(W_in, W_c1, W_c2, wtin, wtc1, wtc2);
  convert_kernel<<<2080, 256, 0, stream>>>(ck, emb, ckb, embb);
  gemm_plain_kernel<<<dim3(64, 4), 256, 0, stream>>>(embb, wtin, b_in, tbl);
  gather_kernel<<<B_ * TP_ / 4, 256, 0, stream>>>(units, resid, vmask, smask, tbl,
                                                  W_in + 512 * 512, W_in + 513 * 512, h0p, h1p);
  conv_gemm_kernel<1, 1><<<4096, 256, 0, stream>>>(h0p, wtc1, b_c1, (void*)h1p);
  conv_gemm_kernel<0, 0><<<4096, 256, 0, stream>>>(h1p, wtc2, b_c2, (void*)h2);
  lnpool_kernel<<<dim3(16, 32), 256, 0, stream>>>(h2, ln_w, ln_b, vmask, smask, Sh, Sh2);
  score_kernel<<<256, 256, 0, stream>>>(h2, ckb, resid, vmask, attn, S0, S1, S2);
  role_kernel<<<B_, 64, 0, stream>>>(S0, S1, S2, sup, out, rv);
  mlp_kernel<<<B_, 512, 0, stream>>>(Sh, Sh2, spc, sup, W_p1, b_p1, W_p2, b_p2, out);
  fit_kernel<<<B_ * T_ / 4, 256, 0, stream>>>(attn, rv, vmask, out);
}